// Round 9
// baseline (211.825 us; speedup 1.0000x reference)
//
#include <hip/hip_runtime.h>
#include <cmath>

typedef _Float16 f16;
typedef _Float16 f16x8 __attribute__((ext_vector_type(8)));
typedef _Float16 f16x4 __attribute__((ext_vector_type(4)));
typedef float    f32x4 __attribute__((ext_vector_type(4)));
typedef unsigned int u32;
typedef u32 u32x4 __attribute__((ext_vector_type(4)));

#define C_   192
#define HH   56
#define WW   56
#define NN   3136
#define BB   8
#define MM   784
#define NHEAD 4
#define HD   48
#define VT_LD 800            // padded key-dim of transposed V (784 + 16)
#define QPB  (BB*NN/64)      // 392 proj blocks, Q path
#define KVPB (BB*MM/64)      // 98 proj blocks, KV path

#define MFMA16(a,b,c) __builtin_amdgcn_mfma_f32_16x16x32_f16(a,b,c,0,0,0)

static __device__ __forceinline__ u32 pkrtz(float a, float b) {
    typedef __fp16 fp16x2 __attribute__((ext_vector_type(2)));
    fp16x2 h = __builtin_amdgcn_cvt_pkrtz(a, b);
    return __builtin_bit_cast(u32, h);
}

// ---------------------------------------------------------------------------
// Setup: blocks 0..575 = fold pointwise into projections (3 x 192 rows),
// blocks 576..703 = zero Vt pad columns m=784..799.  block = 192 threads.
__global__ __launch_bounds__(192) void setup_kernel(
    const float* __restrict__ Wq, const float* __restrict__ Wk,
    const float* __restrict__ Wv, const float* __restrict__ pw_q,
    const float* __restrict__ pw_kv,
    f16* __restrict__ Mq, f16* __restrict__ Mk, f16* __restrict__ Mv,
    f16* __restrict__ vt)
{
    int blk = blockIdx.x, tid = threadIdx.x;
    if (blk < 576) {
        int which = blk / 192, o = blk % 192;
        const float* Wm = which == 0 ? Wq : (which == 1 ? Wk : Wv);
        const float* P  = which == 0 ? pw_q : (which == 1 ? pw_kv : pw_kv + C_*C_);
        f16* Mo         = which == 0 ? Mq : (which == 1 ? Mk : Mv);
        __shared__ float wrow[C_];
        wrow[tid] = Wm[o*C_ + tid];
        __syncthreads();
        float acc = 0.f;
        #pragma unroll 8
        for (int j = 0; j < C_; ++j)
            acc = fmaf(wrow[j], P[j*C_ + tid], acc);
        Mo[o*C_ + tid] = (f16)acc;
    } else {
        int i = (blk - 576)*192 + tid;          // 24576 pad elements exactly
        int b = i / (C_*16);
        int rem = i % (C_*16);
        int c = rem / 16;
        int m = MM + (rem & 15);
        vt[((size_t)b*C_ + c)*VT_LD + m] = (f16)0.f;
    }
}

// ---------------------------------------------------------------------------
// Depthwise 3x3 + BN for both paths in one launch. fp32 compute, f16 out.
__device__ __forceinline__ void dwbn_one(
    const float* __restrict__ x, const float* __restrict__ dw,
    const float* __restrict__ gamma, const float* __restrict__ beta,
    const float* __restrict__ mean,  const float* __restrict__ var,
    f16* __restrict__ out, int OH, int OW, int stride, int idx)
{
    int c4 = idx % (C_/4);
    int sp = idx / (C_/4);
    int ox = sp % OW;
    int t2 = sp / OW;
    int oy = t2 % OH;
    int b  = t2 / OH;
    int c0 = c4*4;
    float4 acc = make_float4(0.f,0.f,0.f,0.f);
    int iy0 = oy*stride - 1;
    int ix0 = ox*stride - 1;
    #pragma unroll
    for (int ky = 0; ky < 3; ++ky) {
        int iy = iy0 + ky;
        if (iy < 0 || iy >= HH) continue;
        #pragma unroll
        for (int kx = 0; kx < 3; ++kx) {
            int ix = ix0 + kx;
            if (ix < 0 || ix >= WW) continue;
            float4 xv = *reinterpret_cast<const float4*>(
                x + ((size_t)b*NN + iy*WW + ix)*C_ + c0);
            int wi = ky*3 + kx;
            acc.x = fmaf(dw[(c0+0)*9 + wi], xv.x, acc.x);
            acc.y = fmaf(dw[(c0+1)*9 + wi], xv.y, acc.y);
            acc.z = fmaf(dw[(c0+2)*9 + wi], xv.z, acc.z);
            acc.w = fmaf(dw[(c0+3)*9 + wi], xv.w, acc.w);
        }
    }
    float i0 = gamma[c0+0]*__frsqrt_rn(var[c0+0] + 1e-5f);
    float i1 = gamma[c0+1]*__frsqrt_rn(var[c0+1] + 1e-5f);
    float i2 = gamma[c0+2]*__frsqrt_rn(var[c0+2] + 1e-5f);
    float i3 = gamma[c0+3]*__frsqrt_rn(var[c0+3] + 1e-5f);
    f16x4 r;
    r[0] = (f16)(acc.x*i0 + (beta[c0+0] - mean[c0+0]*i0));
    r[1] = (f16)(acc.y*i1 + (beta[c0+1] - mean[c0+1]*i1));
    r[2] = (f16)(acc.z*i2 + (beta[c0+2] - mean[c0+2]*i2));
    r[3] = (f16)(acc.w*i3 + (beta[c0+3] - mean[c0+3]*i3));
    *reinterpret_cast<f16x4*>(out + (size_t)idx*4) = r;
}

__global__ __launch_bounds__(256) void dwbn_both(
    const float* __restrict__ x,
    const float* __restrict__ dwq,  const float* __restrict__ gq,
    const float* __restrict__ bq_,  const float* __restrict__ mq,
    const float* __restrict__ vq,
    const float* __restrict__ dwkv, const float* __restrict__ gkv,
    const float* __restrict__ bkv,  const float* __restrict__ mkv,
    const float* __restrict__ vkv,
    f16* __restrict__ uq, f16* __restrict__ ukv)
{
    int idx = blockIdx.x*256 + threadIdx.x;
    const int totq = BB*NN*(C_/4);          // 1204224
    const int totk = BB*MM*(C_/4);          // 301056
    if (idx < totq) {
        dwbn_one(x, dwq, gq, bq_, mq, vq, uq, HH, WW, 1, idx);
    } else {
        int i2 = idx - totq;
        if (i2 < totk)
            dwbn_one(x, dwkv, gkv, bkv, mkv, vkv, ukv, 28, 28, 2, i2);
    }
}

// ---------------------------------------------------------------------------
// All projections, one launch. blocks 0..391: Q path (64 rows each).
// blocks 392..489: KV path — A-fragments loaded once, used for K and V.
// Ping-pong prefetch of B-fragments across the 12 column-tiles.
__global__ __launch_bounds__(256, 1) void proj_all(
    const f16* __restrict__ uq, const f16* __restrict__ ukv,
    const f16* __restrict__ Mq, const f16* __restrict__ Mk,
    const f16* __restrict__ Mv,
    const float* __restrict__ bq, const float* __restrict__ bk,
    const float* __restrict__ bv,
    f16* __restrict__ qb, f16* __restrict__ kb, f16* __restrict__ vt)
{
    int tid  = threadIdx.x;
    int w    = tid >> 6, l = tid & 63;
    int lrow = l & 15,  lgrp = l >> 4;
    int blk  = blockIdx.x;
    bool qpath = blk < QPB;
    const f16* U = qpath ? uq : ukv;
    int r0 = (qpath ? blk : blk - QPB)*64 + w*16;

    const f16* urow = U + (size_t)(r0 + lrow)*C_;
    f16x8 a[6];
    #pragma unroll
    for (int ch = 0; ch < 6; ++ch)
        a[ch] = *(const f16x8*)(urow + ch*32 + lgrp*8);

    f16x8 bfA[6], bfB[6];

    if (qpath) {
        // scale = (1/sqrt(48)) * log2(e)  — attn softmax runs in exp2 domain
        const float qscale = 0.14433756729740643f * 1.4426950408889634f;
        #pragma unroll
        for (int ch = 0; ch < 6; ++ch)
            bfA[ch] = *(const f16x8*)(Mq + (size_t)lrow*C_ + ch*32 + lgrp*8);
        #pragma unroll
        for (int ct = 0; ct < 12; ++ct) {
            f16x8* cur = (ct & 1) ? bfB : bfA;
            f16x8* nxt = (ct & 1) ? bfA : bfB;
            if (ct < 11) {
                const f16* mrow = Mq + (size_t)((ct+1)*16 + lrow)*C_;
                #pragma unroll
                for (int ch = 0; ch < 6; ++ch)
                    nxt[ch] = *(const f16x8*)(mrow + ch*32 + lgrp*8);
            }
            int o = ct*16 + lrow;
            f32x4 acc = {0.f,0.f,0.f,0.f};
            #pragma unroll
            for (int ch = 0; ch < 6; ++ch)
                acc = MFMA16(a[ch], cur[ch], acc);
            float bo = bq[o];
            #pragma unroll
            for (int i = 0; i < 4; ++i)
                qb[(size_t)(r0 + lgrp*4 + i)*C_ + o] = (f16)((acc[i] + bo)*qscale);
        }
    } else {
        #pragma unroll
        for (int ch = 0; ch < 6; ++ch)
            bfA[ch] = *(const f16x8*)(Mk + (size_t)lrow*C_ + ch*32 + lgrp*8);
        #pragma unroll
        for (int ct = 0; ct < 12; ++ct) {            // K projection
            f16x8* cur = (ct & 1) ? bfB : bfA;
            f16x8* nxt = (ct & 1) ? bfA : bfB;
            const f16* nrow = (ct < 11) ? Mk + (size_t)((ct+1)*16 + lrow)*C_
                                        : Mv + (size_t)lrow*C_;
            #pragma unroll
            for (int ch = 0; ch < 6; ++ch)
                nxt[ch] = *(const f16x8*)(nrow + ch*32 + lgrp*8);
            int o = ct*16 + lrow;
            f32x4 acc = {0.f,0.f,0.f,0.f};
            #pragma unroll
            for (int ch = 0; ch < 6; ++ch)
                acc = MFMA16(a[ch], cur[ch], acc);
            float bo = bk[o];
            #pragma unroll
            for (int i = 0; i < 4; ++i)
                kb[(size_t)(r0 + lgrp*4 + i)*C_ + o] = (f16)(acc[i] + bo);
        }
        // V: K-loop's last prefetch (ct=11, odd) put Mv tile 0 into bfA,
        // so the V loop uses the SAME parity as the K loop (even ct -> bfA).
        #pragma unroll
        for (int ct = 0; ct < 12; ++ct) {            // V projection (transposed)
            f16x8* cur = (ct & 1) ? bfB : bfA;
            f16x8* nxt = (ct & 1) ? bfA : bfB;
            if (ct < 11) {
                const f16* mrow = Mv + (size_t)((ct+1)*16 + lrow)*C_;
                #pragma unroll
                for (int ch = 0; ch < 6; ++ch)
                    nxt[ch] = *(const f16x8*)(mrow + ch*32 + lgrp*8);
            }
            int o = ct*16 + lrow;
            f32x4 acc = {0.f,0.f,0.f,0.f};
            #pragma unroll
            for (int ch = 0; ch < 6; ++ch)
                acc = MFMA16(a[ch], cur[ch], acc);
            float bo = bv[o];
            int rg = r0 + lgrp*4;
            int b  = rg / MM, m = rg % MM;            // 784 % 16 == 0, no straddle
            #pragma unroll
            for (int i = 0; i < 4; ++i)
                vt[((size_t)b*C_ + o)*VT_LD + m + i] = (f16)(acc[i] + bo);
        }
    }
}

// ---------------------------------------------------------------------------
// Flash attention R9: 32-key tiles, TRIPLE-buffered (A/B/C) register pipeline
// with sched_barrier(0) fences pinning each prefetch ABOVE the compute phase
// so the pre-RA scheduler cannot sink the loads to their uses (R5-R8 all
// collapsed to 52-124 VGPR with serialized loads -> invariant ~120us).
// Distance-2 prefetch: tile t+2's 7 loads issue during tile t's compute.
struct Tile {
    f16x8 ka0, ka1;   // keys m0+lrow      : d 0..31 | d 32..63
    f16x8 kb0, kb1;   // keys m0+16+lrow
    f16x8 v0, v1, v2; // Vt rows lrow, +16, +32 ; cols m0 + g*8 ..
};

__device__ __forceinline__ void load_tile(
    Tile& T, const f16* __restrict__ kbb, const f16* __restrict__ vbb,
    int m0, int lrow, int g)
{
    const f16* r0 = kbb + (size_t)(m0 + lrow)*C_;
    const f16* r1 = kbb + (size_t)(m0 + 16 + lrow)*C_;
    T.ka0 = *(const f16x8*)(r0 + g*8);
    T.ka1 = *(const f16x8*)(r0 + 32 + g*8);
    T.kb0 = *(const f16x8*)(r1 + g*8);
    T.kb1 = *(const f16x8*)(r1 + 32 + g*8);
    T.v0  = *(const f16x8*)(vbb + m0 + g*8);
    T.v1  = *(const f16x8*)(vbb + 16*VT_LD + m0 + g*8);
    T.v2  = *(const f16x8*)(vbb + 32*VT_LD + m0 + g*8);
}

__device__ __forceinline__ void compute_tile(
    const Tile& T, const f16x8& qf0, const f16x8& qf1,
    float& mrun, float& lrun, f32x4& o0, f32x4& o1, f32x4& o2,
    int la, int lb, bool hi, bool tail)
{
    f32x4 z = {0.f,0.f,0.f,0.f};
    f32x4 s0, s1;
    __builtin_amdgcn_s_setprio(1);
    s0 = MFMA16(T.ka0, qf0, z);  s0 = MFMA16(T.ka1, qf1, s0);
    s1 = MFMA16(T.kb0, qf0, z);  s1 = MFMA16(T.kb1, qf1, s1);
    __builtin_amdgcn_s_setprio(0);

    if (tail) {   // tile 24: keys 784..799 are fake
        #pragma unroll
        for (int r = 0; r < 4; ++r) s1[r] = -1e30f;
    }

    float tmax = fmaxf(fmaxf(fmaxf(s0[0], s0[1]), fmaxf(s0[2], s0[3])),
                       fmaxf(fmaxf(s1[0], s1[1]), fmaxf(s1[2], s1[3])));
    tmax = fmaxf(tmax, __shfl_xor(tmax, 16));
    tmax = fmaxf(tmax, __shfl_xor(tmax, 32));
    float mnew = fmaxf(mrun, tmax);
    float corr = exp2f(mrun - mnew);
    mrun = mnew;
    float psum = 0.f;
    #pragma unroll
    for (int r = 0; r < 4; ++r) {
        s0[r] = exp2f(s0[r] - mnew); psum += s0[r];
        s1[r] = exp2f(s1[r] - mnew); psum += s1[r];
    }
    psum += __shfl_xor(psum, 16);
    psum += __shfl_xor(psum, 32);
    lrun = lrun*corr + psum;

    u32 pk00 = pkrtz(s0[0], s0[1]), pk01 = pkrtz(s0[2], s0[3]);
    u32 pk10 = pkrtz(s1[0], s1[1]), pk11 = pkrtz(s1[2], s1[3]);

    #pragma unroll
    for (int r = 0; r < 4; ++r) { o0[r] *= corr; o1[r] *= corr; o2[r] *= corr; }

    u32 a0  = __shfl(pk00, la), a0h = __shfl(pk10, la);
    u32 a1  = __shfl(pk01, la), a1h = __shfl(pk11, la);
    u32 b0  = __shfl(pk00, lb), b0h = __shfl(pk10, lb);
    u32 b1  = __shfl(pk01, lb), b1h = __shfl(pk11, lb);
    u32x4 uw = { hi ? a0h : a0, hi ? a1h : a1, hi ? b0h : b0, hi ? b1h : b1 };
    f16x8 pb = __builtin_bit_cast(f16x8, uw);

    __builtin_amdgcn_s_setprio(1);
    o0 = MFMA16(T.v0, pb, o0);
    o1 = MFMA16(T.v1, pb, o1);
    o2 = MFMA16(T.v2, pb, o2);
    __builtin_amdgcn_s_setprio(0);
}

// Phase: issue next-tile loads FIRST (pinned by fences), then compute current.
// The counted vmcnt the compiler emits before the NEXT phase's MFMA keeps
// these loads in flight across this phase's softmax/PV.
#define PHASE(CUR, NXT, MPRE, TAIL)                                          \
    __builtin_amdgcn_sched_barrier(0);                                       \
    load_tile(NXT, kbb, vbb, (MPRE), lrow, g);                               \
    __builtin_amdgcn_sched_barrier(0);                                       \
    compute_tile(CUR, qf0, qf1, mrun, lrun, o0, o1, o2, la, lb, hi, TAIL);

__global__ __launch_bounds__(256, 2) void attn_mfma(
    const f16* __restrict__ qb, const f16* __restrict__ kb,
    const f16* __restrict__ vt, float* __restrict__ out)
{
    int tid  = threadIdx.x;
    int w    = tid >> 6, l = tid & 63;
    int lrow = l & 15,  g = l >> 4;
    // XCD swizzle: 1568 = 8*196; 4 (b,h) groups per XCD -> KV L2-resident.
    int swz  = (blockIdx.x & 7)*196 + (blockIdx.x >> 3);
    int bh   = swz / 49, qblk = swz % 49;
    int h    = bh & 3, b = bh >> 2;
    int n0   = qblk*64 + w*16;

    const f16* qrow = qb + ((size_t)b*NN + n0 + lrow)*C_ + h*HD;
    f16x8 qf0 = *(const f16x8*)(qrow + g*8);
    f16x8 qf1 = (f16x8){0,0,0,0,0,0,0,0};
    if (g < 2) qf1 = *(const f16x8*)(qrow + 32 + g*8);

    float mrun = -1e30f, lrun = 0.f;
    f32x4 o0 = {0.f,0.f,0.f,0.f}, o1 = o0, o2 = o0;

    int  la = lrow + ((g & 1) << 5);
    int  lb = la + 16;
    bool hi = g >= 2;

    const f16* kbb = kb + (size_t)b*MM*C_ + h*HD;
    const f16* vbb = vt + ((size_t)b*C_ + h*HD + lrow)*VT_LD;

    Tile A, B, Cc;
    load_tile(A, kbb, vbb, 0,  lrow, g);
    load_tile(B, kbb, vbb, 32, lrow, g);

    // 25 tiles of 32 keys (tile 24 = keys 768..799, upper half masked).
    // Rotation: iter p handles tiles 3p, 3p+1, 3p+2 (m0 = 96p + {0,32,64}).
    for (int p = 0; p < 8; ++p) {
        int t0 = 96*p;
        int pre1 = t0 + 64;                      // -> Cc (used this iter)
        int pre2 = (t0 + 96  > 768) ? 768 : t0 + 96;   // -> A (next iter)
        int pre3 = (t0 + 128 > 768) ? 768 : t0 + 128;  // -> B (next iter)
        PHASE(A,  Cc, pre1, false)
        PHASE(B,  A,  pre2, false)
        PHASE(Cc, B,  pre3, false)
    }
    // tiles 0..23 done; tile 24 (m0=768) is in A.
    __builtin_amdgcn_sched_barrier(0);
    compute_tile(A, qf0, qf1, mrun, lrun, o0, o1, o2, la, lb, hi, true);

    float inv = 1.f / lrun;
    f32x4 r0, r1, r2;
    #pragma unroll
    for (int r = 0; r < 4; ++r) {
        r0[r] = o0[r]*inv; r1[r] = o1[r]*inv; r2[r] = o2[r]*inv;
    }
    float* obase = out + ((size_t)b*NN + n0 + lrow)*C_ + h*HD + g*4;
    *(f32x4*)(obase)      = r0;
    *(f32x4*)(obase + 16) = r1;
    *(f32x4*)(obase + 32) = r2;
}

// ---------------------------------------------------------------------------
extern "C" void kernel_launch(void* const* d_in, const int* in_sizes, int n_in,
                              void* d_out, int out_size, void* d_ws, size_t ws_size,
                              hipStream_t stream)
{
    const float* x     = (const float*)d_in[0];
    const float* dw_q  = (const float*)d_in[3];
    const float* bnqg  = (const float*)d_in[4];
    const float* bnqb  = (const float*)d_in[5];
    const float* bnqm  = (const float*)d_in[6];
    const float* bnqv  = (const float*)d_in[7];
    const float* pw_q  = (const float*)d_in[8];
    const float* dw_kv = (const float*)d_in[9];
    const float* bnkg  = (const float*)d_in[10];
    const float* bnkb  = (const float*)d_in[11];
    const float* bnkm  = (const float*)d_in[12];
    const float* bnkvv = (const float*)d_in[13];
    const float* pw_kv = (const float*)d_in[14];
    const float* Wq    = (const float*)d_in[15];
    const float* bq    = (const float*)d_in[16];
    const float* Wk    = (const float*)d_in[17];
    const float* bk    = (const float*)d_in[18];
    const float* Wv    = (const float*)d_in[19];
    const float* bv    = (const float*)d_in[20];
    float* out = (float*)d_out;

    f16* p   = (f16*)d_ws;
    f16* Mq16  = p;  p += C_*C_;
    f16* Mk16  = p;  p += C_*C_;
    f16* Mv16  = p;  p += C_*C_;
    f16* uq16  = p;  p += (size_t)BB*NN*C_;
    f16* ukv16 = p;  p += (size_t)BB*MM*C_;
    f16* qb16  = p;  p += (size_t)BB*NN*C_ + 256;    // pad: frag tail reads
    f16* kb16  = p;  p += (size_t)BB*MM*C_ + 16384;  // pad: tail-tile prefetch overread
    f16* vt16  = p;  p += (size_t)BB*C_*VT_LD;

    setup_kernel<<<704, 192, 0, stream>>>(
        Wq, Wk, Wv, pw_q, pw_kv, Mq16, Mk16, Mv16, vt16);

    dwbn_both<<<5880, 256, 0, stream>>>(
        x, dw_q, bnqg, bnqb, bnqm, bnqv,
        dw_kv, bnkg, bnkb, bnkm, bnkvv, uq16, ukv16);

    proj_all<<<QPB + KVPB, 256, 0, stream>>>(
        uq16, ukv16, Mq16, Mk16, Mv16, bq, bk, bv, qb16, kb16, vt16);

    attn_mfma<<<1568, 256, 0, stream>>>(qb16, kb16, vt16, out);
}

// Round 10
// 151.126 us; speedup vs baseline: 1.4016x; 1.4016x over previous
//
#include <hip/hip_runtime.h>
#include <cmath>

typedef _Float16 f16;
typedef _Float16 f16x8 __attribute__((ext_vector_type(8)));
typedef _Float16 f16x4 __attribute__((ext_vector_type(4)));
typedef float    f32x4 __attribute__((ext_vector_type(4)));
typedef unsigned int u32;
typedef u32 u32x4 __attribute__((ext_vector_type(4)));

#define C_   192
#define HH   56
#define WW   56
#define NN   3136
#define BB   8
#define MM   784
#define NHEAD 4
#define HD   48
#define VT_LD 832            // padded key-dim of transposed V (784 + 48)
#define QPB  (BB*NN/64)      // 392 proj blocks, Q path
#define KVPB (BB*MM/64)      // 98 proj blocks, KV path

#define MFMA16(a,b,c) __builtin_amdgcn_mfma_f32_16x16x32_f16(a,b,c,0,0,0)

static __device__ __forceinline__ u32 pkrtz(float a, float b) {
    typedef __fp16 fp16x2 __attribute__((ext_vector_type(2)));
    fp16x2 h = __builtin_amdgcn_cvt_pkrtz(a, b);
    return __builtin_bit_cast(u32, h);
}

// async global->LDS, 16B per lane; LDS dst = wave-uniform base + lane*16
static __device__ __forceinline__ void gload16(const void* g, void* l) {
    __builtin_amdgcn_global_load_lds(
        (const __attribute__((address_space(1))) unsigned int*)g,
        (__attribute__((address_space(3))) unsigned int*)l, 16, 0, 0);
}

// ---------------------------------------------------------------------------
// Setup: blocks 0..575 = fold pointwise into projections (3 x 192 rows),
// blocks 576..959 = zero Vt pad columns m=784..831.  block = 192 threads.
__global__ __launch_bounds__(192) void setup_kernel(
    const float* __restrict__ Wq, const float* __restrict__ Wk,
    const float* __restrict__ Wv, const float* __restrict__ pw_q,
    const float* __restrict__ pw_kv,
    f16* __restrict__ Mq, f16* __restrict__ Mk, f16* __restrict__ Mv,
    f16* __restrict__ vt)
{
    int blk = blockIdx.x, tid = threadIdx.x;
    if (blk < 576) {
        int which = blk / 192, o = blk % 192;
        const float* Wm = which == 0 ? Wq : (which == 1 ? Wk : Wv);
        const float* P  = which == 0 ? pw_q : (which == 1 ? pw_kv : pw_kv + C_*C_);
        f16* Mo         = which == 0 ? Mq : (which == 1 ? Mk : Mv);
        __shared__ float wrow[C_];
        wrow[tid] = Wm[o*C_ + tid];
        __syncthreads();
        float acc = 0.f;
        #pragma unroll 8
        for (int j = 0; j < C_; ++j)
            acc = fmaf(wrow[j], P[j*C_ + tid], acc);
        Mo[o*C_ + tid] = (f16)acc;
    } else {
        int i = (blk - 576)*192 + tid;          // BB*C_*48 = 73728 exactly
        int b = i / (C_*48);
        int rem = i % (C_*48);
        int c = rem / 48;
        int m = MM + (rem % 48);
        vt[((size_t)b*C_ + c)*VT_LD + m] = (f16)0.f;
    }
}

// ---------------------------------------------------------------------------
// Depthwise 3x3 + BN for both paths in one launch. fp32 compute, f16 out.
__device__ __forceinline__ void dwbn_one(
    const float* __restrict__ x, const float* __restrict__ dw,
    const float* __restrict__ gamma, const float* __restrict__ beta,
    const float* __restrict__ mean,  const float* __restrict__ var,
    f16* __restrict__ out, int OH, int OW, int stride, int idx)
{
    int c4 = idx % (C_/4);
    int sp = idx / (C_/4);
    int ox = sp % OW;
    int t2 = sp / OW;
    int oy = t2 % OH;
    int b  = t2 / OH;
    int c0 = c4*4;
    float4 acc = make_float4(0.f,0.f,0.f,0.f);
    int iy0 = oy*stride - 1;
    int ix0 = ox*stride - 1;
    #pragma unroll
    for (int ky = 0; ky < 3; ++ky) {
        int iy = iy0 + ky;
        if (iy < 0 || iy >= HH) continue;
        #pragma unroll
        for (int kx = 0; kx < 3; ++kx) {
            int ix = ix0 + kx;
            if (ix < 0 || ix >= WW) continue;
            float4 xv = *reinterpret_cast<const float4*>(
                x + ((size_t)b*NN + iy*WW + ix)*C_ + c0);
            int wi = ky*3 + kx;
            acc.x = fmaf(dw[(c0+0)*9 + wi], xv.x, acc.x);
            acc.y = fmaf(dw[(c0+1)*9 + wi], xv.y, acc.y);
            acc.z = fmaf(dw[(c0+2)*9 + wi], xv.z, acc.z);
            acc.w = fmaf(dw[(c0+3)*9 + wi], xv.w, acc.w);
        }
    }
    float i0 = gamma[c0+0]*__frsqrt_rn(var[c0+0] + 1e-5f);
    float i1 = gamma[c0+1]*__frsqrt_rn(var[c0+1] + 1e-5f);
    float i2 = gamma[c0+2]*__frsqrt_rn(var[c0+2] + 1e-5f);
    float i3 = gamma[c0+3]*__frsqrt_rn(var[c0+3] + 1e-5f);
    f16x4 r;
    r[0] = (f16)(acc.x*i0 + (beta[c0+0] - mean[c0+0]*i0));
    r[1] = (f16)(acc.y*i1 + (beta[c0+1] - mean[c0+1]*i1));
    r[2] = (f16)(acc.z*i2 + (beta[c0+2] - mean[c0+2]*i2));
    r[3] = (f16)(acc.w*i3 + (beta[c0+3] - mean[c0+3]*i3));
    *reinterpret_cast<f16x4*>(out + (size_t)idx*4) = r;
}

__global__ __launch_bounds__(256) void dwbn_both(
    const float* __restrict__ x,
    const float* __restrict__ dwq,  const float* __restrict__ gq,
    const float* __restrict__ bq_,  const float* __restrict__ mq,
    const float* __restrict__ vq,
    const float* __restrict__ dwkv, const float* __restrict__ gkv,
    const float* __restrict__ bkv,  const float* __restrict__ mkv,
    const float* __restrict__ vkv,
    f16* __restrict__ uq, f16* __restrict__ ukv)
{
    int idx = blockIdx.x*256 + threadIdx.x;
    const int totq = BB*NN*(C_/4);          // 1204224
    const int totk = BB*MM*(C_/4);          // 301056
    if (idx < totq) {
        dwbn_one(x, dwq, gq, bq_, mq, vq, uq, HH, WW, 1, idx);
    } else {
        int i2 = idx - totq;
        if (i2 < totk)
            dwbn_one(x, dwkv, gkv, bkv, mkv, vkv, ukv, 28, 28, 2, i2);
    }
}

// ---------------------------------------------------------------------------
// All projections, one launch. blocks 0..391: Q path (64 rows each).
// blocks 392..489: KV path — A-fragments loaded once, used for K and V.
__global__ __launch_bounds__(256, 1) void proj_all(
    const f16* __restrict__ uq, const f16* __restrict__ ukv,
    const f16* __restrict__ Mq, const f16* __restrict__ Mk,
    const f16* __restrict__ Mv,
    const float* __restrict__ bq, const float* __restrict__ bk,
    const float* __restrict__ bv,
    f16* __restrict__ qb, f16* __restrict__ kb, f16* __restrict__ vt)
{
    int tid  = threadIdx.x;
    int w    = tid >> 6, l = tid & 63;
    int lrow = l & 15,  lgrp = l >> 4;
    int blk  = blockIdx.x;
    bool qpath = blk < QPB;
    const f16* U = qpath ? uq : ukv;
    int r0 = (qpath ? blk : blk - QPB)*64 + w*16;

    const f16* urow = U + (size_t)(r0 + lrow)*C_;
    f16x8 a[6];
    #pragma unroll
    for (int ch = 0; ch < 6; ++ch)
        a[ch] = *(const f16x8*)(urow + ch*32 + lgrp*8);

    f16x8 bfA[6], bfB[6];

    if (qpath) {
        // scale = (1/sqrt(48)) * log2(e)  — attn softmax runs in exp2 domain
        const float qscale = 0.14433756729740643f * 1.4426950408889634f;
        #pragma unroll
        for (int ch = 0; ch < 6; ++ch)
            bfA[ch] = *(const f16x8*)(Mq + (size_t)lrow*C_ + ch*32 + lgrp*8);
        #pragma unroll
        for (int ct = 0; ct < 12; ++ct) {
            f16x8* cur = (ct & 1) ? bfB : bfA;
            f16x8* nxt = (ct & 1) ? bfA : bfB;
            if (ct < 11) {
                const f16* mrow = Mq + (size_t)((ct+1)*16 + lrow)*C_;
                #pragma unroll
                for (int ch = 0; ch < 6; ++ch)
                    nxt[ch] = *(const f16x8*)(mrow + ch*32 + lgrp*8);
            }
            int o = ct*16 + lrow;
            f32x4 acc = {0.f,0.f,0.f,0.f};
            #pragma unroll
            for (int ch = 0; ch < 6; ++ch)
                acc = MFMA16(a[ch], cur[ch], acc);
            float bo = bq[o];
            #pragma unroll
            for (int i = 0; i < 4; ++i)
                qb[(size_t)(r0 + lgrp*4 + i)*C_ + o] = (f16)((acc[i] + bo)*qscale);
        }
    } else {
        #pragma unroll
        for (int ch = 0; ch < 6; ++ch)
            bfA[ch] = *(const f16x8*)(Mk + (size_t)lrow*C_ + ch*32 + lgrp*8);
        #pragma unroll
        for (int ct = 0; ct < 12; ++ct) {            // K projection
            f16x8* cur = (ct & 1) ? bfB : bfA;
            f16x8* nxt = (ct & 1) ? bfA : bfB;
            const f16* nrow = (ct < 11) ? Mk + (size_t)((ct+1)*16 + lrow)*C_
                                        : Mv + (size_t)lrow*C_;
            #pragma unroll
            for (int ch = 0; ch < 6; ++ch)
                nxt[ch] = *(const f16x8*)(nrow + ch*32 + lgrp*8);
            int o = ct*16 + lrow;
            f32x4 acc = {0.f,0.f,0.f,0.f};
            #pragma unroll
            for (int ch = 0; ch < 6; ++ch)
                acc = MFMA16(a[ch], cur[ch], acc);
            float bo = bk[o];
            #pragma unroll
            for (int i = 0; i < 4; ++i)
                kb[(size_t)(r0 + lgrp*4 + i)*C_ + o] = (f16)(acc[i] + bo);
        }
        // V: K-loop's last prefetch (ct=11, odd) put Mv tile 0 into bfA,
        // so the V loop uses the SAME parity as the K loop (even ct -> bfA).
        #pragma unroll
        for (int ct = 0; ct < 12; ++ct) {            // V projection (transposed)
            f16x8* cur = (ct & 1) ? bfB : bfA;
            f16x8* nxt = (ct & 1) ? bfA : bfB;
            if (ct < 11) {
                const f16* mrow = Mv + (size_t)((ct+1)*16 + lrow)*C_;
                #pragma unroll
                for (int ch = 0; ch < 6; ++ch)
                    nxt[ch] = *(const f16x8*)(mrow + ch*32 + lgrp*8);
            }
            int o = ct*16 + lrow;
            f32x4 acc = {0.f,0.f,0.f,0.f};
            #pragma unroll
            for (int ch = 0; ch < 6; ++ch)
                acc = MFMA16(a[ch], cur[ch], acc);
            float bo = bv[o];
            int rg = r0 + lgrp*4;
            int b  = rg / MM, m = rg % MM;            // 784 % 16 == 0, no straddle
            #pragma unroll
            for (int i = 0; i < 4; ++i)
                vt[((size_t)b*C_ + o)*VT_LD + m + i] = (f16)(acc[i] + bo);
        }
    }
}

// ---------------------------------------------------------------------------
// Flash attention R10: LDS-staged K/V via async global_load_lds (VGPR-free,
// un-sinkable), double-buffered, counted vmcnt (never 0 in-loop), raw
// s_barrier (NOT __syncthreads — that drains vmcnt(0)).  4 waves x 16
// queries; 13 tiles of 64 keys (tile 12: 16 real keys, blocks 1-3 masked).
// LDS layout [rows][64] f16 with chunk XOR-swizzle  p = c ^ (row&7),
// applied on the global SOURCE address (LDS write is linear DMA) and on
// the ds_read address — bank-conflict-free per m214's attn recipe.

__device__ __forceinline__ void stage_tile(
    int w, int l, f16* ldsKb, f16* ldsVb,
    const f16* __restrict__ kbb, const f16* __restrict__ vbb, int m0)
{
    int rr = l >> 3, p = l & 7;
    #pragma unroll
    for (int j = 0; j < 4; ++j) {
        int u = w + j*4;
        if (u < 8) {                      // K rows 8u..8u+7
            int r = u*8 + rr;
            int c = p ^ (r & 7);
            gload16(kbb + (size_t)(m0 + r)*C_ + c*8, ldsKb + u*512);
        } else if (u < 14) {              // V rows (d) 8(u-8)..+7
            int d = (u-8)*8 + rr;
            int c = p ^ (d & 7);
            gload16(vbb + (size_t)d*VT_LD + m0 + c*8, ldsVb + (u-8)*512);
        }
    }
}

__device__ __forceinline__ void compute_tile64(
    const f16* ldsKb, const f16* ldsVb,
    const f16x8& qf0, const f16x8& qf1,
    float& mrun, float& lrun, f32x4& o0, f32x4& o1, f32x4& o2,
    int lrow, int g, int la, int lb, bool hi, bool tail)
{
    const char* kB = (const char*)ldsKb;
    const char* vB = (const char*)ldsVb;
    f32x4 z = {0.f,0.f,0.f,0.f};
    f32x4 s0, s1, s2, s3;
    int sw = (lrow & 7);
    int cA = (g ^ sw) << 4, cB = ((4+g) ^ sw) << 4;

    __builtin_amdgcn_s_setprio(1);
    {   const char* rb = kB + lrow*128;
        s0 = MFMA16(*(const f16x8*)(rb + cA), qf0, z);
        s0 = MFMA16(*(const f16x8*)(rb + cB), qf1, s0); }
    {   const char* rb = kB + (16+lrow)*128;
        s1 = MFMA16(*(const f16x8*)(rb + cA), qf0, z);
        s1 = MFMA16(*(const f16x8*)(rb + cB), qf1, s1); }
    {   const char* rb = kB + (32+lrow)*128;
        s2 = MFMA16(*(const f16x8*)(rb + cA), qf0, z);
        s2 = MFMA16(*(const f16x8*)(rb + cB), qf1, s2); }
    {   const char* rb = kB + (48+lrow)*128;
        s3 = MFMA16(*(const f16x8*)(rb + cA), qf0, z);
        s3 = MFMA16(*(const f16x8*)(rb + cB), qf1, s3); }
    __builtin_amdgcn_s_setprio(0);

    if (tail) {   // keys >= 784 live in blocks 1..3 of tile 12
        f32x4 neg = {-1e30f,-1e30f,-1e30f,-1e30f};
        s1 = neg; s2 = neg; s3 = neg;
    }

    float t0 = fmaxf(fmaxf(s0[0], s0[1]), fmaxf(s0[2], s0[3]));
    float t1 = fmaxf(fmaxf(s1[0], s1[1]), fmaxf(s1[2], s1[3]));
    float t2 = fmaxf(fmaxf(s2[0], s2[1]), fmaxf(s2[2], s2[3]));
    float t3 = fmaxf(fmaxf(s3[0], s3[1]), fmaxf(s3[2], s3[3]));
    float tmax = fmaxf(fmaxf(t0, t1), fmaxf(t2, t3));
    tmax = fmaxf(tmax, __shfl_xor(tmax, 16));
    tmax = fmaxf(tmax, __shfl_xor(tmax, 32));
    float mnew = fmaxf(mrun, tmax);
    float corr = exp2f(mrun - mnew);
    mrun = mnew;
    float psum = 0.f;
    #pragma unroll
    for (int r = 0; r < 4; ++r) {
        s0[r] = exp2f(s0[r] - mnew); psum += s0[r];
        s1[r] = exp2f(s1[r] - mnew); psum += s1[r];
        s2[r] = exp2f(s2[r] - mnew); psum += s2[r];
        s3[r] = exp2f(s3[r] - mnew); psum += s3[r];
    }
    psum += __shfl_xor(psum, 16);
    psum += __shfl_xor(psum, 32);
    lrun = lrun*corr + psum;

    u32 p00 = pkrtz(s0[0], s0[1]), p01 = pkrtz(s0[2], s0[3]);
    u32 p10 = pkrtz(s1[0], s1[1]), p11 = pkrtz(s1[2], s1[3]);
    u32 p20 = pkrtz(s2[0], s2[1]), p21 = pkrtz(s2[2], s2[3]);
    u32 p30 = pkrtz(s3[0], s3[1]), p31 = pkrtz(s3[2], s3[3]);

    #pragma unroll
    for (int r = 0; r < 4; ++r) { o0[r] *= corr; o1[r] *= corr; o2[r] *= corr; }

    // PV chunk kc=0: key blocks 0,1
    {
        int cv = (0*4 + g);
        int b0o = ((cv ^ sw) << 4);
        f16x8 v0 = *(const f16x8*)(vB + lrow*128      + b0o);
        f16x8 v1 = *(const f16x8*)(vB + (16+lrow)*128 + b0o);
        f16x8 v2 = *(const f16x8*)(vB + (32+lrow)*128 + b0o);
        u32 a0  = __shfl(p00, la), a0h = __shfl(p10, la);
        u32 a1  = __shfl(p01, la), a1h = __shfl(p11, la);
        u32 b0  = __shfl(p00, lb), b0h = __shfl(p10, lb);
        u32 b1  = __shfl(p01, lb), b1h = __shfl(p11, lb);
        u32x4 uw = { hi ? a0h : a0, hi ? a1h : a1, hi ? b0h : b0, hi ? b1h : b1 };
        f16x8 pb = __builtin_bit_cast(f16x8, uw);
        __builtin_amdgcn_s_setprio(1);
        o0 = MFMA16(v0, pb, o0);
        o1 = MFMA16(v1, pb, o1);
        o2 = MFMA16(v2, pb, o2);
        __builtin_amdgcn_s_setprio(0);
    }
    // PV chunk kc=1: key blocks 2,3
    {
        int cv = (1*4 + g);
        int b1o = ((cv ^ sw) << 4);
        f16x8 v0 = *(const f16x8*)(vB + lrow*128      + b1o);
        f16x8 v1 = *(const f16x8*)(vB + (16+lrow)*128 + b1o);
        f16x8 v2 = *(const f16x8*)(vB + (32+lrow)*128 + b1o);
        u32 a0  = __shfl(p20, la), a0h = __shfl(p30, la);
        u32 a1  = __shfl(p21, la), a1h = __shfl(p31, la);
        u32 b0  = __shfl(p20, lb), b0h = __shfl(p30, lb);
        u32 b1  = __shfl(p21, lb), b1h = __shfl(p31, lb);
        u32x4 uw = { hi ? a0h : a0, hi ? a1h : a1, hi ? b0h : b0, hi ? b1h : b1 };
        f16x8 pb = __builtin_bit_cast(f16x8, uw);
        __builtin_amdgcn_s_setprio(1);
        o0 = MFMA16(v0, pb, o0);
        o1 = MFMA16(v1, pb, o1);
        o2 = MFMA16(v2, pb, o2);
        __builtin_amdgcn_s_setprio(0);
    }
}

__global__ __launch_bounds__(256, 2) void attn_mfma(
    const f16* __restrict__ qb, const f16* __restrict__ kb,
    const f16* __restrict__ vt, float* __restrict__ out)
{
    __shared__ __align__(16) f16 ldsK[2][64*64];   // 16 KB
    __shared__ __align__(16) f16 ldsV[2][48*64];   // 12 KB

    int tid  = threadIdx.x;
    int w    = tid >> 6, l = tid & 63;
    int lrow = l & 15,  g = l >> 4;
    // XCD swizzle: 1568 = 8*196; 4 (b,h) groups per XCD -> KV L2-resident.
    int swz  = (blockIdx.x & 7)*196 + (blockIdx.x >> 3);
    int bh   = swz / 49, qblk = swz % 49;
    int h    = bh & 3, b = bh >> 2;
    int n0   = qblk*64 + w*16;

    const f16* kbb = kb + (size_t)b*MM*C_ + h*HD;
    const f16* vbb = vt + ((size_t)b*C_ + h*HD)*VT_LD;

    // Q fragments; force the compiler's Q-load waitcnt to land HERE (before
    // any staging) so in-loop vmcnt counting stays ours alone.
    const f16* qrow = qb + ((size_t)b*NN + n0 + lrow)*C_ + h*HD;
    f16x8 qf0 = *(const f16x8*)(qrow + g*8);
    f16x8 qf1 = (f16x8){0,0,0,0,0,0,0,0};
    if (g < 2) qf1 = *(const f16x8*)(qrow + 32 + g*8);
    asm volatile("" :: "v"(qf0), "v"(qf1));

    float mrun = -1e30f, lrun = 0.f;
    f32x4 o0 = {0.f,0.f,0.f,0.f}, o1 = o0, o2 = o0;

    int  la = lrow + ((g & 1) << 5);
    int  lb = la + 16;
    bool hi = g >= 2;

    // prologue: stage tile 0 into buffer 0
    stage_tile(w, l, &ldsK[0][0], &ldsV[0][0], kbb, vbb, 0);

    for (int t = 0; t < 13; ++t) {
        int nb = t & 1;
        if (t < 12)
            stage_tile(w, l, &ldsK[nb^1][0], &ldsV[nb^1][0], kbb, vbb, (t+1)*64);
        __builtin_amdgcn_sched_barrier(0);
        if (t < 12) {
            if (w < 2) asm volatile("s_waitcnt vmcnt(4)" ::: "memory");
            else       asm volatile("s_waitcnt vmcnt(3)" ::: "memory");
        } else {
            asm volatile("s_waitcnt vmcnt(0)" ::: "memory");
        }
        __builtin_amdgcn_s_barrier();
        __builtin_amdgcn_sched_barrier(0);
        compute_tile64(&ldsK[nb][0], &ldsV[nb][0], qf0, qf1,
                       mrun, lrun, o0, o1, o2, lrow, g, la, lb, hi, t == 12);
        __builtin_amdgcn_sched_barrier(0);
        __builtin_amdgcn_s_barrier();
    }

    float inv = 1.f / lrun;
    f32x4 r0, r1, r2;
    #pragma unroll
    for (int r = 0; r < 4; ++r) {
        r0[r] = o0[r]*inv; r1[r] = o1[r]*inv; r2[r] = o2[r]*inv;
    }
    float* obase = out + ((size_t)b*NN + n0 + lrow)*C_ + h*HD + g*4;
    *(f32x4*)(obase)      = r0;
    *(f32x4*)(obase + 16) = r1;
    *(f32x4*)(obase + 32) = r2;
}

// ---------------------------------------------------------------------------
extern "C" void kernel_launch(void* const* d_in, const int* in_sizes, int n_in,
                              void* d_out, int out_size, void* d_ws, size_t ws_size,
                              hipStream_t stream)
{
    const float* x     = (const float*)d_in[0];
    const float* dw_q  = (const float*)d_in[3];
    const float* bnqg  = (const float*)d_in[4];
    const float* bnqb  = (const float*)d_in[5];
    const float* bnqm  = (const float*)d_in[6];
    const float* bnqv  = (const float*)d_in[7];
    const float* pw_q  = (const float*)d_in[8];
    const float* dw_kv = (const float*)d_in[9];
    const float* bnkg  = (const float*)d_in[10];
    const float* bnkb  = (const float*)d_in[11];
    const float* bnkm  = (const float*)d_in[12];
    const float* bnkvv = (const float*)d_in[13];
    const float* pw_kv = (const float*)d_in[14];
    const float* Wq    = (const float*)d_in[15];
    const float* bq    = (const float*)d_in[16];
    const float* Wk    = (const float*)d_in[17];
    const float* bk    = (const float*)d_in[18];
    const float* Wv    = (const float*)d_in[19];
    const float* bv    = (const float*)d_in[20];
    float* out = (float*)d_out;

    f16* p   = (f16*)d_ws;
    f16* Mq16  = p;  p += C_*C_;
    f16* Mk16  = p;  p += C_*C_;
    f16* Mv16  = p;  p += C_*C_;
    f16* uq16  = p;  p += (size_t)BB*NN*C_;
    f16* ukv16 = p;  p += (size_t)BB*MM*C_;
    f16* qb16  = p;  p += (size_t)BB*NN*C_ + 256;    // pad: frag tail reads
    f16* kb16  = p;  p += (size_t)BB*MM*C_ + 16384;  // pad: tail-tile staging overread
    f16* vt16  = p;  p += (size_t)BB*C_*VT_LD;

    setup_kernel<<<960, 192, 0, stream>>>(
        Wq, Wk, Wv, pw_q, pw_kv, Mq16, Mk16, Mv16, vt16);

    dwbn_both<<<5880, 256, 0, stream>>>(
        x, dw_q, bnqg, bnqb, bnqm, bnqv,
        dw_kv, bnkg, bnkb, bnkm, bnkvv, uq16, ukv16);

    proj_all<<<QPB + KVPB, 256, 0, stream>>>(
        uq16, ukv16, Mq16, Mk16, Mv16, bq, bk, bv, qb16, kb16, vt16);

    attn_mfma<<<1568, 256, 0, stream>>>(qb16, kb16, vt16, out);
}

// Round 11
// 146.390 us; speedup vs baseline: 1.4470x; 1.0324x over previous
//
#include <hip/hip_runtime.h>
#include <cmath>

typedef _Float16 f16;
typedef _Float16 f16x8 __attribute__((ext_vector_type(8)));
typedef _Float16 f16x4 __attribute__((ext_vector_type(4)));
typedef float    f32x4 __attribute__((ext_vector_type(4)));
typedef unsigned int u32;
typedef u32 u32x4 __attribute__((ext_vector_type(4)));

#define C_   192
#define HH   56
#define WW   56
#define NN   3136
#define BB   8
#define MM   784
#define NHEAD 4
#define HD   48
#define VT_LD 832            // padded key-dim of transposed V (784 + 48)
#define QPB  (BB*NN/64)      // 392 proj blocks, Q path
#define KVPB (BB*MM/64)      // 98 proj blocks, KV path

#define MFMA16(a,b,c) __builtin_amdgcn_mfma_f32_16x16x32_f16(a,b,c,0,0,0)

static __device__ __forceinline__ u32 pkrtz(float a, float b) {
    typedef __fp16 fp16x2 __attribute__((ext_vector_type(2)));
    fp16x2 h = __builtin_amdgcn_cvt_pkrtz(a, b);
    return __builtin_bit_cast(u32, h);
}

// async global->LDS, 16B per lane; LDS dst = wave-uniform base + lane*16
static __device__ __forceinline__ void gload16(const void* g, void* l) {
    __builtin_amdgcn_global_load_lds(
        (const __attribute__((address_space(1))) unsigned int*)g,
        (__attribute__((address_space(3))) unsigned int*)l, 16, 0, 0);
}

// ---------------------------------------------------------------------------
// Depthwise 3x3 + BN, fp32 compute, f16 out.
__device__ __forceinline__ void dwbn_one(
    const float* __restrict__ x, const float* __restrict__ dw,
    const float* __restrict__ gamma, const float* __restrict__ beta,
    const float* __restrict__ mean,  const float* __restrict__ var,
    f16* __restrict__ out, int OH, int OW, int stride, int idx)
{
    int c4 = idx % (C_/4);
    int sp = idx / (C_/4);
    int ox = sp % OW;
    int t2 = sp / OW;
    int oy = t2 % OH;
    int b  = t2 / OH;
    int c0 = c4*4;
    float4 acc = make_float4(0.f,0.f,0.f,0.f);
    int iy0 = oy*stride - 1;
    int ix0 = ox*stride - 1;
    #pragma unroll
    for (int ky = 0; ky < 3; ++ky) {
        int iy = iy0 + ky;
        if (iy < 0 || iy >= HH) continue;
        #pragma unroll
        for (int kx = 0; kx < 3; ++kx) {
            int ix = ix0 + kx;
            if (ix < 0 || ix >= WW) continue;
            float4 xv = *reinterpret_cast<const float4*>(
                x + ((size_t)b*NN + iy*WW + ix)*C_ + c0);
            int wi = ky*3 + kx;
            acc.x = fmaf(dw[(c0+0)*9 + wi], xv.x, acc.x);
            acc.y = fmaf(dw[(c0+1)*9 + wi], xv.y, acc.y);
            acc.z = fmaf(dw[(c0+2)*9 + wi], xv.z, acc.z);
            acc.w = fmaf(dw[(c0+3)*9 + wi], xv.w, acc.w);
        }
    }
    float i0 = gamma[c0+0]*__frsqrt_rn(var[c0+0] + 1e-5f);
    float i1 = gamma[c0+1]*__frsqrt_rn(var[c0+1] + 1e-5f);
    float i2 = gamma[c0+2]*__frsqrt_rn(var[c0+2] + 1e-5f);
    float i3 = gamma[c0+3]*__frsqrt_rn(var[c0+3] + 1e-5f);
    f16x4 r;
    r[0] = (f16)(acc.x*i0 + (beta[c0+0] - mean[c0+0]*i0));
    r[1] = (f16)(acc.y*i1 + (beta[c0+1] - mean[c0+1]*i1));
    r[2] = (f16)(acc.z*i2 + (beta[c0+2] - mean[c0+2]*i2));
    r[3] = (f16)(acc.w*i3 + (beta[c0+3] - mean[c0+3]*i3));
    *reinterpret_cast<f16x4*>(out + (size_t)idx*4) = r;
}

// ---------------------------------------------------------------------------
// Fused prep: dwbn (both paths) + pointwise-fold (3 matrices) + Vt pad zero.
// blocks 0..4703         : dwbn Q path
// blocks 4704..5879      : dwbn KV path
// blocks 5880..6455      : M-fold (192 threads active)
// blocks 6456..6743      : Vt pad columns 784..831
__global__ __launch_bounds__(256) void prep_all(
    const float* __restrict__ x,
    const float* __restrict__ dwq,  const float* __restrict__ gq,
    const float* __restrict__ bq_,  const float* __restrict__ mq,
    const float* __restrict__ vq,
    const float* __restrict__ dwkv, const float* __restrict__ gkv,
    const float* __restrict__ bkv,  const float* __restrict__ mkv,
    const float* __restrict__ vkv,
    const float* __restrict__ Wq, const float* __restrict__ Wk,
    const float* __restrict__ Wv, const float* __restrict__ pw_q,
    const float* __restrict__ pw_kv,
    f16* __restrict__ uq, f16* __restrict__ ukv,
    f16* __restrict__ Mq, f16* __restrict__ Mk, f16* __restrict__ Mv,
    f16* __restrict__ vt)
{
    int blk = blockIdx.x, tid = threadIdx.x;
    const int QB = BB*NN*(C_/4)/256;   // 4704
    const int KB = BB*MM*(C_/4)/256;   // 1176
    if (blk < QB) {
        dwbn_one(x, dwq, gq, bq_, mq, vq, uq, HH, WW, 1, blk*256 + tid);
    } else if (blk < QB + KB) {
        dwbn_one(x, dwkv, gkv, bkv, mkv, vkv, ukv, 28, 28, 2,
                 (blk - QB)*256 + tid);
    } else if (blk < QB + KB + 576) {
        int fb = blk - QB - KB;
        int which = fb / 192, o = fb % 192;
        const float* Wm = which == 0 ? Wq : (which == 1 ? Wk : Wv);
        const float* P  = which == 0 ? pw_q : (which == 1 ? pw_kv : pw_kv + C_*C_);
        f16* Mo         = which == 0 ? Mq : (which == 1 ? Mk : Mv);
        __shared__ float wrow[C_];
        if (tid < C_) wrow[tid] = Wm[o*C_ + tid];
        __syncthreads();
        if (tid < C_) {
            float acc = 0.f;
            #pragma unroll 8
            for (int j = 0; j < C_; ++j)
                acc = fmaf(wrow[j], P[j*C_ + tid], acc);
            Mo[o*C_ + tid] = (f16)acc;
        }
    } else {
        int i = (blk - QB - KB - 576)*256 + tid;   // BB*C_*48 = 73728 exactly
        int b = i / (C_*48);
        int rem = i % (C_*48);
        int c = rem / 48;
        int m = MM + (rem % 48);
        vt[((size_t)b*C_ + c)*VT_LD + m] = (f16)0.f;
    }
}

// ---------------------------------------------------------------------------
// All projections, one launch. blocks 0..391: Q path (64 rows each).
// blocks 392..489: KV path — A-fragments loaded once, used for K and V.
// Q/K use SWAPPED operands mfma(M,U): lane then holds 4 consecutive output
// columns for its row -> one packed 8B f16x4 store per ct (was 4 scalar 2B
// stores at 384B stride). V keeps order (4 consecutive m) and packs too.
__global__ __launch_bounds__(256, 1) void proj_all(
    const f16* __restrict__ uq, const f16* __restrict__ ukv,
    const f16* __restrict__ Mq, const f16* __restrict__ Mk,
    const f16* __restrict__ Mv,
    const float* __restrict__ bq, const float* __restrict__ bk,
    const float* __restrict__ bv,
    f16* __restrict__ qb, f16* __restrict__ kb, f16* __restrict__ vt)
{
    int tid  = threadIdx.x;
    int w    = tid >> 6, l = tid & 63;
    int lrow = l & 15,  lgrp = l >> 4;
    int blk  = blockIdx.x;
    bool qpath = blk < QPB;
    const f16* U = qpath ? uq : ukv;
    int r0 = (qpath ? blk : blk - QPB)*64 + w*16;

    const f16* urow = U + (size_t)(r0 + lrow)*C_;
    f16x8 a[6];
    #pragma unroll
    for (int ch = 0; ch < 6; ++ch)
        a[ch] = *(const f16x8*)(urow + ch*32 + lgrp*8);

    f16x8 bfA[6], bfB[6];

    if (qpath) {
        // scale = (1/sqrt(48)) * log2(e)  — attn softmax runs in exp2 domain
        const float qscale = 0.14433756729740643f * 1.4426950408889634f;
        #pragma unroll
        for (int ch = 0; ch < 6; ++ch)
            bfA[ch] = *(const f16x8*)(Mq + (size_t)lrow*C_ + ch*32 + lgrp*8);
        #pragma unroll
        for (int ct = 0; ct < 12; ++ct) {
            f16x8* cur = (ct & 1) ? bfB : bfA;
            f16x8* nxt = (ct & 1) ? bfA : bfB;
            if (ct < 11) {
                const f16* mrow = Mq + (size_t)((ct+1)*16 + lrow)*C_;
                #pragma unroll
                for (int ch = 0; ch < 6; ++ch)
                    nxt[ch] = *(const f16x8*)(mrow + ch*32 + lgrp*8);
            }
            f32x4 acc = {0.f,0.f,0.f,0.f};
            #pragma unroll
            for (int ch = 0; ch < 6; ++ch)
                acc = MFMA16(cur[ch], a[ch], acc);          // swapped
            float4 bo = *(const float4*)(bq + ct*16 + lgrp*4);
            f16x4 st;
            st[0] = (f16)((acc[0] + bo.x)*qscale);
            st[1] = (f16)((acc[1] + bo.y)*qscale);
            st[2] = (f16)((acc[2] + bo.z)*qscale);
            st[3] = (f16)((acc[3] + bo.w)*qscale);
            *(f16x4*)(qb + (size_t)(r0 + lrow)*C_ + ct*16 + lgrp*4) = st;
        }
    } else {
        #pragma unroll
        for (int ch = 0; ch < 6; ++ch)
            bfA[ch] = *(const f16x8*)(Mk + (size_t)lrow*C_ + ch*32 + lgrp*8);
        #pragma unroll
        for (int ct = 0; ct < 12; ++ct) {            // K projection (swapped)
            f16x8* cur = (ct & 1) ? bfB : bfA;
            f16x8* nxt = (ct & 1) ? bfA : bfB;
            const f16* nrow = (ct < 11) ? Mk + (size_t)((ct+1)*16 + lrow)*C_
                                        : Mv + (size_t)lrow*C_;
            #pragma unroll
            for (int ch = 0; ch < 6; ++ch)
                nxt[ch] = *(const f16x8*)(nrow + ch*32 + lgrp*8);
            f32x4 acc = {0.f,0.f,0.f,0.f};
            #pragma unroll
            for (int ch = 0; ch < 6; ++ch)
                acc = MFMA16(cur[ch], a[ch], acc);
            float4 bo = *(const float4*)(bk + ct*16 + lgrp*4);
            f16x4 st;
            st[0] = (f16)(acc[0] + bo.x);
            st[1] = (f16)(acc[1] + bo.y);
            st[2] = (f16)(acc[2] + bo.z);
            st[3] = (f16)(acc[3] + bo.w);
            *(f16x4*)(kb + (size_t)(r0 + lrow)*C_ + ct*16 + lgrp*4) = st;
        }
        // V: K-loop's last prefetch (ct=11, odd) put Mv tile 0 into bfA;
        // V loop uses same parity (even ct -> bfA). NOT swapped: lane's 4
        // acc entries are 4 consecutive m -> packed store into Vt row o.
        #pragma unroll
        for (int ct = 0; ct < 12; ++ct) {            // V projection (transposed)
            f16x8* cur = (ct & 1) ? bfB : bfA;
            f16x8* nxt = (ct & 1) ? bfA : bfB;
            if (ct < 11) {
                const f16* mrow = Mv + (size_t)((ct+1)*16 + lrow)*C_;
                #pragma unroll
                for (int ch = 0; ch < 6; ++ch)
                    nxt[ch] = *(const f16x8*)(mrow + ch*32 + lgrp*8);
            }
            int o = ct*16 + lrow;
            f32x4 acc = {0.f,0.f,0.f,0.f};
            #pragma unroll
            for (int ch = 0; ch < 6; ++ch)
                acc = MFMA16(a[ch], cur[ch], acc);
            float bo = bv[o];
            int rg = r0 + lgrp*4;
            int b  = rg / MM, m = rg % MM;            // 784 % 16 == 0, no straddle
            f16x4 st;
            st[0] = (f16)(acc[0] + bo);
            st[1] = (f16)(acc[1] + bo);
            st[2] = (f16)(acc[2] + bo);
            st[3] = (f16)(acc[3] + bo);
            *(f16x4*)(vt + ((size_t)b*C_ + o)*VT_LD + m) = st;
        }
    }
}

// ---------------------------------------------------------------------------
// Flash attention R10 (unchanged): LDS-staged K/V via async global_load_lds,
// double-buffered, counted vmcnt, raw s_barrier, XOR-swizzled LDS.
__device__ __forceinline__ void stage_tile(
    int w, int l, f16* ldsKb, f16* ldsVb,
    const f16* __restrict__ kbb, const f16* __restrict__ vbb, int m0)
{
    int rr = l >> 3, p = l & 7;
    #pragma unroll
    for (int j = 0; j < 4; ++j) {
        int u = w + j*4;
        if (u < 8) {                      // K rows 8u..8u+7
            int r = u*8 + rr;
            int c = p ^ (r & 7);
            gload16(kbb + (size_t)(m0 + r)*C_ + c*8, ldsKb + u*512);
        } else if (u < 14) {              // V rows (d) 8(u-8)..+7
            int d = (u-8)*8 + rr;
            int c = p ^ (d & 7);
            gload16(vbb + (size_t)d*VT_LD + m0 + c*8, ldsVb + (u-8)*512);
        }
    }
}

__device__ __forceinline__ void compute_tile64(
    const f16* ldsKb, const f16* ldsVb,
    const f16x8& qf0, const f16x8& qf1,
    float& mrun, float& lrun, f32x4& o0, f32x4& o1, f32x4& o2,
    int lrow, int g, int la, int lb, bool hi, bool tail)
{
    const char* kB = (const char*)ldsKb;
    const char* vB = (const char*)ldsVb;
    f32x4 z = {0.f,0.f,0.f,0.f};
    f32x4 s0, s1, s2, s3;
    int sw = (lrow & 7);
    int cA = (g ^ sw) << 4, cB = ((4+g) ^ sw) << 4;

    __builtin_amdgcn_s_setprio(1);
    {   const char* rb = kB + lrow*128;
        s0 = MFMA16(*(const f16x8*)(rb + cA), qf0, z);
        s0 = MFMA16(*(const f16x8*)(rb + cB), qf1, s0); }
    {   const char* rb = kB + (16+lrow)*128;
        s1 = MFMA16(*(const f16x8*)(rb + cA), qf0, z);
        s1 = MFMA16(*(const f16x8*)(rb + cB), qf1, s1); }
    {   const char* rb = kB + (32+lrow)*128;
        s2 = MFMA16(*(const f16x8*)(rb + cA), qf0, z);
        s2 = MFMA16(*(const f16x8*)(rb + cB), qf1, s2); }
    {   const char* rb = kB + (48+lrow)*128;
        s3 = MFMA16(*(const f16x8*)(rb + cA), qf0, z);
        s3 = MFMA16(*(const f16x8*)(rb + cB), qf1, s3); }
    __builtin_amdgcn_s_setprio(0);

    if (tail) {   // keys >= 784 live in blocks 1..3 of tile 12
        f32x4 neg = {-1e30f,-1e30f,-1e30f,-1e30f};
        s1 = neg; s2 = neg; s3 = neg;
    }

    float t0 = fmaxf(fmaxf(s0[0], s0[1]), fmaxf(s0[2], s0[3]));
    float t1 = fmaxf(fmaxf(s1[0], s1[1]), fmaxf(s1[2], s1[3]));
    float t2 = fmaxf(fmaxf(s2[0], s2[1]), fmaxf(s2[2], s2[3]));
    float t3 = fmaxf(fmaxf(s3[0], s3[1]), fmaxf(s3[2], s3[3]));
    float tmax = fmaxf(fmaxf(t0, t1), fmaxf(t2, t3));
    tmax = fmaxf(tmax, __shfl_xor(tmax, 16));
    tmax = fmaxf(tmax, __shfl_xor(tmax, 32));
    float mnew = fmaxf(mrun, tmax);
    float corr = exp2f(mrun - mnew);
    mrun = mnew;
    float psum = 0.f;
    #pragma unroll
    for (int r = 0; r < 4; ++r) {
        s0[r] = exp2f(s0[r] - mnew); psum += s0[r];
        s1[r] = exp2f(s1[r] - mnew); psum += s1[r];
        s2[r] = exp2f(s2[r] - mnew); psum += s2[r];
        s3[r] = exp2f(s3[r] - mnew); psum += s3[r];
    }
    psum += __shfl_xor(psum, 16);
    psum += __shfl_xor(psum, 32);
    lrun = lrun*corr + psum;

    u32 p00 = pkrtz(s0[0], s0[1]), p01 = pkrtz(s0[2], s0[3]);
    u32 p10 = pkrtz(s1[0], s1[1]), p11 = pkrtz(s1[2], s1[3]);
    u32 p20 = pkrtz(s2[0], s2[1]), p21 = pkrtz(s2[2], s2[3]);
    u32 p30 = pkrtz(s3[0], s3[1]), p31 = pkrtz(s3[2], s3[3]);

    #pragma unroll
    for (int r = 0; r < 4; ++r) { o0[r] *= corr; o1[r] *= corr; o2[r] *= corr; }

    // PV chunk kc=0: key blocks 0,1
    {
        int cv = (0*4 + g);
        int b0o = ((cv ^ sw) << 4);
        f16x8 v0 = *(const f16x8*)(vB + lrow*128      + b0o);
        f16x8 v1 = *(const f16x8*)(vB + (16+lrow)*128 + b0o);
        f16x8 v2 = *(const f16x8*)(vB + (32+lrow)*128 + b0o);
        u32 a0  = __shfl(p00, la), a0h = __shfl(p10, la);
        u32 a1  = __shfl(p01, la), a1h = __shfl(p11, la);
        u32 b0  = __shfl(p00, lb), b0h = __shfl(p10, lb);
        u32 b1  = __shfl(p01, lb), b1h = __shfl(p11, lb);
        u32x4 uw = { hi ? a0h : a0, hi ? a1h : a1, hi ? b0h : b0, hi ? b1h : b1 };
        f16x8 pb = __builtin_bit_cast(f16x8, uw);
        __builtin_amdgcn_s_setprio(1);
        o0 = MFMA16(v0, pb, o0);
        o1 = MFMA16(v1, pb, o1);
        o2 = MFMA16(v2, pb, o2);
        __builtin_amdgcn_s_setprio(0);
    }
    // PV chunk kc=1: key blocks 2,3
    {
        int cv = (1*4 + g);
        int b1o = ((cv ^ sw) << 4);
        f16x8 v0 = *(const f16x8*)(vB + lrow*128      + b1o);
        f16x8 v1 = *(const f16x8*)(vB + (16+lrow)*128 + b1o);
        f16x8 v2 = *(const f16x8*)(vB + (32+lrow)*128 + b1o);
        u32 a0  = __shfl(p20, la), a0h = __shfl(p30, la);
        u32 a1  = __shfl(p21, la), a1h = __shfl(p31, la);
        u32 b0  = __shfl(p20, lb), b0h = __shfl(p30, lb);
        u32 b1  = __shfl(p21, lb), b1h = __shfl(p31, lb);
        u32x4 uw = { hi ? a0h : a0, hi ? a1h : a1, hi ? b0h : b0, hi ? b1h : b1 };
        f16x8 pb = __builtin_bit_cast(f16x8, uw);
        __builtin_amdgcn_s_setprio(1);
        o0 = MFMA16(v0, pb, o0);
        o1 = MFMA16(v1, pb, o1);
        o2 = MFMA16(v2, pb, o2);
        __builtin_amdgcn_s_setprio(0);
    }
}

__global__ __launch_bounds__(256, 2) void attn_mfma(
    const f16* __restrict__ qb, const f16* __restrict__ kb,
    const f16* __restrict__ vt, float* __restrict__ out)
{
    __shared__ __align__(16) f16 ldsK[2][64*64];   // 16 KB
    __shared__ __align__(16) f16 ldsV[2][48*64];   // 12 KB

    int tid  = threadIdx.x;
    int w    = tid >> 6, l = tid & 63;
    int lrow = l & 15,  g = l >> 4;
    // XCD swizzle: 1568 = 8*196; 4 (b,h) groups per XCD -> KV L2-resident.
    int swz  = (blockIdx.x & 7)*196 + (blockIdx.x >> 3);
    int bh   = swz / 49, qblk = swz % 49;
    int h    = bh & 3, b = bh >> 2;
    int n0   = qblk*64 + w*16;

    const f16* kbb = kb + (size_t)b*MM*C_ + h*HD;
    const f16* vbb = vt + ((size_t)b*C_ + h*HD)*VT_LD;

    const f16* qrow = qb + ((size_t)b*NN + n0 + lrow)*C_ + h*HD;
    f16x8 qf0 = *(const f16x8*)(qrow + g*8);
    f16x8 qf1 = (f16x8){0,0,0,0,0,0,0,0};
    if (g < 2) qf1 = *(const f16x8*)(qrow + 32 + g*8);
    asm volatile("" :: "v"(qf0), "v"(qf1));

    float mrun = -1e30f, lrun = 0.f;
    f32x4 o0 = {0.f,0.f,0.f,0.f}, o1 = o0, o2 = o0;

    int  la = lrow + ((g & 1) << 5);
    int  lb = la + 16;
    bool hi = g >= 2;

    // prologue: stage tile 0 into buffer 0
    stage_tile(w, l, &ldsK[0][0], &ldsV[0][0], kbb, vbb, 0);

    for (int t = 0; t < 13; ++t) {
        int nb = t & 1;
        if (t < 12)
            stage_tile(w, l, &ldsK[nb^1][0], &ldsV[nb^1][0], kbb, vbb, (t+1)*64);
        __builtin_amdgcn_sched_barrier(0);
        if (t < 12) {
            if (w < 2) asm volatile("s_waitcnt vmcnt(4)" ::: "memory");
            else       asm volatile("s_waitcnt vmcnt(3)" ::: "memory");
        } else {
            asm volatile("s_waitcnt vmcnt(0)" ::: "memory");
        }
        __builtin_amdgcn_s_barrier();
        __builtin_amdgcn_sched_barrier(0);
        compute_tile64(&ldsK[nb][0], &ldsV[nb][0], qf0, qf1,
                       mrun, lrun, o0, o1, o2, lrow, g, la, lb, hi, t == 12);
        __builtin_amdgcn_sched_barrier(0);
        __builtin_amdgcn_s_barrier();
    }

    float inv = 1.f / lrun;
    f32x4 r0, r1, r2;
    #pragma unroll
    for (int r = 0; r < 4; ++r) {
        r0[r] = o0[r]*inv; r1[r] = o1[r]*inv; r2[r] = o2[r]*inv;
    }
    float* obase = out + ((size_t)b*NN + n0 + lrow)*C_ + h*HD + g*4;
    *(f32x4*)(obase)      = r0;
    *(f32x4*)(obase + 16) = r1;
    *(f32x4*)(obase + 32) = r2;
}

// ---------------------------------------------------------------------------
extern "C" void kernel_launch(void* const* d_in, const int* in_sizes, int n_in,
                              void* d_out, int out_size, void* d_ws, size_t ws_size,
                              hipStream_t stream)
{
    const float* x     = (const float*)d_in[0];
    const float* dw_q  = (const float*)d_in[3];
    const float* bnqg  = (const float*)d_in[4];
    const float* bnqb  = (const float*)d_in[5];
    const float* bnqm  = (const float*)d_in[6];
    const float* bnqv  = (const float*)d_in[7];
    const float* pw_q  = (const float*)d_in[8];
    const float* dw_kv = (const float*)d_in[9];
    const float* bnkg  = (const float*)d_in[10];
    const float* bnkb  = (const float*)d_in[11];
    const float* bnkm  = (const float*)d_in[12];
    const float* bnkvv = (const float*)d_in[13];
    const float* pw_kv = (const float*)d_in[14];
    const float* Wq    = (const float*)d_in[15];
    const float* bq    = (const float*)d_in[16];
    const float* Wk    = (const float*)d_in[17];
    const float* bk    = (const float*)d_in[18];
    const float* Wv    = (const float*)d_in[19];
    const float* bv    = (const float*)d_in[20];
    float* out = (float*)d_out;

    f16* p   = (f16*)d_ws;
    f16* Mq16  = p;  p += C_*C_;
    f16* Mk16  = p;  p += C_*C_;
    f16* Mv16  = p;  p += C_*C_;
    f16* uq16  = p;  p += (size_t)BB*NN*C_;
    f16* ukv16 = p;  p += (size_t)BB*MM*C_;
    f16* qb16  = p;  p += (size_t)BB*NN*C_ + 256;    // pad: frag tail reads
    f16* kb16  = p;  p += (size_t)BB*MM*C_ + 16384;  // pad: tail-tile staging overread
    f16* vt16  = p;  p += (size_t)BB*C_*VT_LD;

    prep_all<<<6744, 256, 0, stream>>>(
        x, dw_q, bnqg, bnqb, bnqm, bnqv,
        dw_kv, bnkg, bnkb, bnkm, bnkvv,
        Wq, Wk, Wv, pw_q, pw_kv,
        uq16, ukv16, Mq16, Mk16, Mv16, vt16);

    proj_all<<<QPB + KVPB, 256, 0, stream>>>(
        uq16, ukv16, Mq16, Mk16, Mv16, bq, bk, bv, qb16, kb16, vt16);

    attn_mfma<<<1568, 256, 0, stream>>>(qb16, kb16, vt16, out);
}

// Round 12
// 118.486 us; speedup vs baseline: 1.7878x; 1.2355x over previous
//
#include <hip/hip_runtime.h>
#include <cmath>

typedef _Float16 f16;
typedef _Float16 f16x8 __attribute__((ext_vector_type(8)));
typedef _Float16 f16x4 __attribute__((ext_vector_type(4)));
typedef float    f32x4 __attribute__((ext_vector_type(4)));
typedef unsigned int u32;
typedef u32 u32x4 __attribute__((ext_vector_type(4)));

#define C_   192
#define HH   56
#define WW   56
#define NN   3136
#define BB   8
#define MM   784
#define NHEAD 4
#define HD   48
#define VT_LD 832            // padded key-dim of transposed V (784 + 48)
#define QPB  (BB*NN/64)      // 392 proj blocks, Q path
#define KVPB (BB*MM/64)      // 98 proj blocks, KV path

#define MFMA16(a,b,c) __builtin_amdgcn_mfma_f32_16x16x32_f16(a,b,c,0,0,0)

static __device__ __forceinline__ u32 pkrtz(float a, float b) {
    typedef __fp16 fp16x2 __attribute__((ext_vector_type(2)));
    fp16x2 h = __builtin_amdgcn_cvt_pkrtz(a, b);
    return __builtin_bit_cast(u32, h);
}

// async global->LDS, 16B per lane; LDS dst = wave-uniform base + lane*16
static __device__ __forceinline__ void gload16(const void* g, void* l) {
    __builtin_amdgcn_global_load_lds(
        (const __attribute__((address_space(1))) unsigned int*)g,
        (__attribute__((address_space(3))) unsigned int*)l, 16, 0, 0);
}

// ---------------------------------------------------------------------------
// Depthwise 3x3 + BN, fp32 compute, f16 out. Weights come from LDS (staged
// coalesced), BN params via coalesced float4 loads — the R11 version's 36
// scalar 144B-stride dw loads were ~48 L1 transactions EACH (= 65us kernel).
__device__ __forceinline__ void dwbn_one(
    const float* __restrict__ x, const float* __restrict__ dwL,
    const float* __restrict__ gamma, const float* __restrict__ beta,
    const float* __restrict__ mean,  const float* __restrict__ var,
    f16* __restrict__ out, int OH, int OW, int stride, int idx)
{
    int c4 = idx % (C_/4);
    int sp = idx / (C_/4);
    int ox = sp % OW;
    int t2 = sp / OW;
    int oy = t2 % OH;
    int b  = t2 / OH;
    int c0 = c4*4;

    // 36 weights (4 channels x 9 taps) as 9 LDS float4 reads, static idx
    float4 w4[9];
    #pragma unroll
    for (int j = 0; j < 9; ++j)
        w4[j] = *(const float4*)&dwL[c4*40 + j*4];
    const float* wf = (const float*)w4;   // wf[cc*9 + wi], all static below

    float4 g4 = *(const float4*)(gamma + c0);
    float4 be4 = *(const float4*)(beta + c0);
    float4 m4 = *(const float4*)(mean + c0);
    float4 v4 = *(const float4*)(var  + c0);

    float4 acc = make_float4(0.f,0.f,0.f,0.f);
    int iy0 = oy*stride - 1;
    int ix0 = ox*stride - 1;
    #pragma unroll
    for (int ky = 0; ky < 3; ++ky) {
        int iy = iy0 + ky;
        if (iy < 0 || iy >= HH) continue;
        #pragma unroll
        for (int kx = 0; kx < 3; ++kx) {
            int ix = ix0 + kx;
            if (ix < 0 || ix >= WW) continue;
            float4 xv = *reinterpret_cast<const float4*>(
                x + ((size_t)b*NN + iy*WW + ix)*C_ + c0);
            const int wi = ky*3 + kx;
            acc.x = fmaf(wf[ 0 + wi], xv.x, acc.x);
            acc.y = fmaf(wf[ 9 + wi], xv.y, acc.y);
            acc.z = fmaf(wf[18 + wi], xv.z, acc.z);
            acc.w = fmaf(wf[27 + wi], xv.w, acc.w);
        }
    }
    float i0 = g4.x*__frsqrt_rn(v4.x + 1e-5f);
    float i1 = g4.y*__frsqrt_rn(v4.y + 1e-5f);
    float i2 = g4.z*__frsqrt_rn(v4.z + 1e-5f);
    float i3 = g4.w*__frsqrt_rn(v4.w + 1e-5f);
    f16x4 r;
    r[0] = (f16)(acc.x*i0 + (be4.x - m4.x*i0));
    r[1] = (f16)(acc.y*i1 + (be4.y - m4.y*i1));
    r[2] = (f16)(acc.z*i2 + (be4.z - m4.z*i2));
    r[3] = (f16)(acc.w*i3 + (be4.w - m4.w*i3));
    *reinterpret_cast<f16x4*>(out + (size_t)idx*4) = r;
}

// ---------------------------------------------------------------------------
// Fused prep: dwbn (both paths) + pointwise-fold (3 matrices) + Vt pad zero.
// blocks 0..4703         : dwbn Q path
// blocks 4704..5879      : dwbn KV path
// blocks 5880..6455      : M-fold (192 threads active)
// blocks 6456..6743      : Vt pad columns 784..831
__global__ __launch_bounds__(256) void prep_all(
    const float* __restrict__ x,
    const float* __restrict__ dwq,  const float* __restrict__ gq,
    const float* __restrict__ bq_,  const float* __restrict__ mq,
    const float* __restrict__ vq,
    const float* __restrict__ dwkv, const float* __restrict__ gkv,
    const float* __restrict__ bkv,  const float* __restrict__ mkv,
    const float* __restrict__ vkv,
    const float* __restrict__ Wq, const float* __restrict__ Wk,
    const float* __restrict__ Wv, const float* __restrict__ pw_q,
    const float* __restrict__ pw_kv,
    f16* __restrict__ uq, f16* __restrict__ ukv,
    f16* __restrict__ Mq, f16* __restrict__ Mk, f16* __restrict__ Mv,
    f16* __restrict__ vt)
{
    int blk = blockIdx.x, tid = threadIdx.x;
    const int QB = BB*NN*(C_/4)/256;   // 4704
    const int KB = BB*MM*(C_/4)/256;   // 1176
    if (blk < QB + KB) {
        bool qp = blk < QB;
        __shared__ __align__(16) float dwL[48*40];
        const float* dwg = qp ? dwq : dwkv;
        // stage 1728 floats (432 float4s), coalesced; layout [c4][40] padded
        for (int i = tid; i < 432; i += 256) {
            int f  = i*4;
            int c4 = f/36, r = f%36;        // r % 4 == 0 -> aligned slot
            *(float4*)&dwL[c4*40 + r] = *(const float4*)(dwg + f);
        }
        __syncthreads();
        if (qp)
            dwbn_one(x, dwL, gq, bq_, mq, vq, uq, HH, WW, 1, blk*256 + tid);
        else
            dwbn_one(x, dwL, gkv, bkv, mkv, vkv, ukv, 28, 28, 2,
                     (blk - QB)*256 + tid);
    } else if (blk < QB + KB + 576) {
        int fb = blk - QB - KB;
        int which = fb / 192, o = fb % 192;
        const float* Wm = which == 0 ? Wq : (which == 1 ? Wk : Wv);
        const float* P  = which == 0 ? pw_q : (which == 1 ? pw_kv : pw_kv + C_*C_);
        f16* Mo         = which == 0 ? Mq : (which == 1 ? Mk : Mv);
        __shared__ float wrow[C_];
        if (tid < C_) wrow[tid] = Wm[o*C_ + tid];
        __syncthreads();
        if (tid < C_) {
            float acc = 0.f;
            #pragma unroll 8
            for (int j = 0; j < C_; ++j)
                acc = fmaf(wrow[j], P[j*C_ + tid], acc);
            Mo[o*C_ + tid] = (f16)acc;
        }
    } else {
        int i = (blk - QB - KB - 576)*256 + tid;   // BB*C_*48 = 73728 exactly
        int b = i / (C_*48);
        int rem = i % (C_*48);
        int c = rem / 48;
        int m = MM + (rem % 48);
        vt[((size_t)b*C_ + c)*VT_LD + m] = (f16)0.f;
    }
}

// ---------------------------------------------------------------------------
// All projections, one launch. blocks 0..391: Q path (64 rows each).
// blocks 392..489: KV path — A-fragments loaded once, used for K and V.
__global__ __launch_bounds__(256, 1) void proj_all(
    const f16* __restrict__ uq, const f16* __restrict__ ukv,
    const f16* __restrict__ Mq, const f16* __restrict__ Mk,
    const f16* __restrict__ Mv,
    const float* __restrict__ bq, const float* __restrict__ bk,
    const float* __restrict__ bv,
    f16* __restrict__ qb, f16* __restrict__ kb, f16* __restrict__ vt)
{
    int tid  = threadIdx.x;
    int w    = tid >> 6, l = tid & 63;
    int lrow = l & 15,  lgrp = l >> 4;
    int blk  = blockIdx.x;
    bool qpath = blk < QPB;
    const f16* U = qpath ? uq : ukv;
    int r0 = (qpath ? blk : blk - QPB)*64 + w*16;

    const f16* urow = U + (size_t)(r0 + lrow)*C_;
    f16x8 a[6];
    #pragma unroll
    for (int ch = 0; ch < 6; ++ch)
        a[ch] = *(const f16x8*)(urow + ch*32 + lgrp*8);

    f16x8 bfA[6], bfB[6];

    if (qpath) {
        // scale = (1/sqrt(48)) * log2(e)  — attn softmax runs in exp2 domain
        const float qscale = 0.14433756729740643f * 1.4426950408889634f;
        #pragma unroll
        for (int ch = 0; ch < 6; ++ch)
            bfA[ch] = *(const f16x8*)(Mq + (size_t)lrow*C_ + ch*32 + lgrp*8);
        #pragma unroll
        for (int ct = 0; ct < 12; ++ct) {
            f16x8* cur = (ct & 1) ? bfB : bfA;
            f16x8* nxt = (ct & 1) ? bfA : bfB;
            if (ct < 11) {
                const f16* mrow = Mq + (size_t)((ct+1)*16 + lrow)*C_;
                #pragma unroll
                for (int ch = 0; ch < 6; ++ch)
                    nxt[ch] = *(const f16x8*)(mrow + ch*32 + lgrp*8);
            }
            f32x4 acc = {0.f,0.f,0.f,0.f};
            #pragma unroll
            for (int ch = 0; ch < 6; ++ch)
                acc = MFMA16(cur[ch], a[ch], acc);          // swapped
            float4 bo = *(const float4*)(bq + ct*16 + lgrp*4);
            f16x4 st;
            st[0] = (f16)((acc[0] + bo.x)*qscale);
            st[1] = (f16)((acc[1] + bo.y)*qscale);
            st[2] = (f16)((acc[2] + bo.z)*qscale);
            st[3] = (f16)((acc[3] + bo.w)*qscale);
            *(f16x4*)(qb + (size_t)(r0 + lrow)*C_ + ct*16 + lgrp*4) = st;
        }
    } else {
        #pragma unroll
        for (int ch = 0; ch < 6; ++ch)
            bfA[ch] = *(const f16x8*)(Mk + (size_t)lrow*C_ + ch*32 + lgrp*8);
        #pragma unroll
        for (int ct = 0; ct < 12; ++ct) {            // K projection (swapped)
            f16x8* cur = (ct & 1) ? bfB : bfA;
            f16x8* nxt = (ct & 1) ? bfA : bfB;
            const f16* nrow = (ct < 11) ? Mk + (size_t)((ct+1)*16 + lrow)*C_
                                        : Mv + (size_t)lrow*C_;
            #pragma unroll
            for (int ch = 0; ch < 6; ++ch)
                nxt[ch] = *(const f16x8*)(nrow + ch*32 + lgrp*8);
            f32x4 acc = {0.f,0.f,0.f,0.f};
            #pragma unroll
            for (int ch = 0; ch < 6; ++ch)
                acc = MFMA16(cur[ch], a[ch], acc);
            float4 bo = *(const float4*)(bk + ct*16 + lgrp*4);
            f16x4 st;
            st[0] = (f16)(acc[0] + bo.x);
            st[1] = (f16)(acc[1] + bo.y);
            st[2] = (f16)(acc[2] + bo.z);
            st[3] = (f16)(acc[3] + bo.w);
            *(f16x4*)(kb + (size_t)(r0 + lrow)*C_ + ct*16 + lgrp*4) = st;
        }
        // V: K-loop's last prefetch (ct=11, odd) put Mv tile 0 into bfA;
        // V loop uses same parity (even ct -> bfA). NOT swapped: lane's 4
        // acc entries are 4 consecutive m -> packed store into Vt row o.
        #pragma unroll
        for (int ct = 0; ct < 12; ++ct) {            // V projection (transposed)
            f16x8* cur = (ct & 1) ? bfB : bfA;
            f16x8* nxt = (ct & 1) ? bfA : bfB;
            if (ct < 11) {
                const f16* mrow = Mv + (size_t)((ct+1)*16 + lrow)*C_;
                #pragma unroll
                for (int ch = 0; ch < 6; ++ch)
                    nxt[ch] = *(const f16x8*)(mrow + ch*32 + lgrp*8);
            }
            int o = ct*16 + lrow;
            f32x4 acc = {0.f,0.f,0.f,0.f};
            #pragma unroll
            for (int ch = 0; ch < 6; ++ch)
                acc = MFMA16(a[ch], cur[ch], acc);
            float bo = bv[o];
            int rg = r0 + lgrp*4;
            int b  = rg / MM, m = rg % MM;            // 784 % 16 == 0, no straddle
            f16x4 st;
            st[0] = (f16)(acc[0] + bo);
            st[1] = (f16)(acc[1] + bo);
            st[2] = (f16)(acc[2] + bo);
            st[3] = (f16)(acc[3] + bo);
            *(f16x4*)(vt + ((size_t)b*C_ + o)*VT_LD + m) = st;
        }
    }
}

// ---------------------------------------------------------------------------
// Flash attention (R10, unchanged): LDS-staged K/V via async global_load_lds,
// double-buffered, counted vmcnt, raw s_barrier, XOR-swizzled LDS.
__device__ __forceinline__ void stage_tile(
    int w, int l, f16* ldsKb, f16* ldsVb,
    const f16* __restrict__ kbb, const f16* __restrict__ vbb, int m0)
{
    int rr = l >> 3, p = l & 7;
    #pragma unroll
    for (int j = 0; j < 4; ++j) {
        int u = w + j*4;
        if (u < 8) {                      // K rows 8u..8u+7
            int r = u*8 + rr;
            int c = p ^ (r & 7);
            gload16(kbb + (size_t)(m0 + r)*C_ + c*8, ldsKb + u*512);
        } else if (u < 14) {              // V rows (d) 8(u-8)..+7
            int d = (u-8)*8 + rr;
            int c = p ^ (d & 7);
            gload16(vbb + (size_t)d*VT_LD + m0 + c*8, ldsVb + (u-8)*512);
        }
    }
}

__device__ __forceinline__ void compute_tile64(
    const f16* ldsKb, const f16* ldsVb,
    const f16x8& qf0, const f16x8& qf1,
    float& mrun, float& lrun, f32x4& o0, f32x4& o1, f32x4& o2,
    int lrow, int g, int la, int lb, bool hi, bool tail)
{
    const char* kB = (const char*)ldsKb;
    const char* vB = (const char*)ldsVb;
    f32x4 z = {0.f,0.f,0.f,0.f};
    f32x4 s0, s1, s2, s3;
    int sw = (lrow & 7);
    int cA = (g ^ sw) << 4, cB = ((4+g) ^ sw) << 4;

    __builtin_amdgcn_s_setprio(1);
    {   const char* rb = kB + lrow*128;
        s0 = MFMA16(*(const f16x8*)(rb + cA), qf0, z);
        s0 = MFMA16(*(const f16x8*)(rb + cB), qf1, s0); }
    {   const char* rb = kB + (16+lrow)*128;
        s1 = MFMA16(*(const f16x8*)(rb + cA), qf0, z);
        s1 = MFMA16(*(const f16x8*)(rb + cB), qf1, s1); }
    {   const char* rb = kB + (32+lrow)*128;
        s2 = MFMA16(*(const f16x8*)(rb + cA), qf0, z);
        s2 = MFMA16(*(const f16x8*)(rb + cB), qf1, s2); }
    {   const char* rb = kB + (48+lrow)*128;
        s3 = MFMA16(*(const f16x8*)(rb + cA), qf0, z);
        s3 = MFMA16(*(const f16x8*)(rb + cB), qf1, s3); }
    __builtin_amdgcn_s_setprio(0);

    if (tail) {   // keys >= 784 live in blocks 1..3 of tile 12
        f32x4 neg = {-1e30f,-1e30f,-1e30f,-1e30f};
        s1 = neg; s2 = neg; s3 = neg;
    }

    float t0 = fmaxf(fmaxf(s0[0], s0[1]), fmaxf(s0[2], s0[3]));
    float t1 = fmaxf(fmaxf(s1[0], s1[1]), fmaxf(s1[2], s1[3]));
    float t2 = fmaxf(fmaxf(s2[0], s2[1]), fmaxf(s2[2], s2[3]));
    float t3 = fmaxf(fmaxf(s3[0], s3[1]), fmaxf(s3[2], s3[3]));
    float tmax = fmaxf(fmaxf(t0, t1), fmaxf(t2, t3));
    tmax = fmaxf(tmax, __shfl_xor(tmax, 16));
    tmax = fmaxf(tmax, __shfl_xor(tmax, 32));
    float mnew = fmaxf(mrun, tmax);
    float corr = exp2f(mrun - mnew);
    mrun = mnew;
    float psum = 0.f;
    #pragma unroll
    for (int r = 0; r < 4; ++r) {
        s0[r] = exp2f(s0[r] - mnew); psum += s0[r];
        s1[r] = exp2f(s1[r] - mnew); psum += s1[r];
        s2[r] = exp2f(s2[r] - mnew); psum += s2[r];
        s3[r] = exp2f(s3[r] - mnew); psum += s3[r];
    }
    psum += __shfl_xor(psum, 16);
    psum += __shfl_xor(psum, 32);
    lrun = lrun*corr + psum;

    u32 p00 = pkrtz(s0[0], s0[1]), p01 = pkrtz(s0[2], s0[3]);
    u32 p10 = pkrtz(s1[0], s1[1]), p11 = pkrtz(s1[2], s1[3]);
    u32 p20 = pkrtz(s2[0], s2[1]), p21 = pkrtz(s2[2], s2[3]);
    u32 p30 = pkrtz(s3[0], s3[1]), p31 = pkrtz(s3[2], s3[3]);

    #pragma unroll
    for (int r = 0; r < 4; ++r) { o0[r] *= corr; o1[r] *= corr; o2[r] *= corr; }

    // PV chunk kc=0: key blocks 0,1
    {
        int cv = (0*4 + g);
        int b0o = ((cv ^ sw) << 4);
        f16x8 v0 = *(const f16x8*)(vB + lrow*128      + b0o);
        f16x8 v1 = *(const f16x8*)(vB + (16+lrow)*128 + b0o);
        f16x8 v2 = *(const f16x8*)(vB + (32+lrow)*128 + b0o);
        u32 a0  = __shfl(p00, la), a0h = __shfl(p10, la);
        u32 a1  = __shfl(p01, la), a1h = __shfl(p11, la);
        u32 b0  = __shfl(p00, lb), b0h = __shfl(p10, lb);
        u32 b1  = __shfl(p01, lb), b1h = __shfl(p11, lb);
        u32x4 uw = { hi ? a0h : a0, hi ? a1h : a1, hi ? b0h : b0, hi ? b1h : b1 };
        f16x8 pb = __builtin_bit_cast(f16x8, uw);
        __builtin_amdgcn_s_setprio(1);
        o0 = MFMA16(v0, pb, o0);
        o1 = MFMA16(v1, pb, o1);
        o2 = MFMA16(v2, pb, o2);
        __builtin_amdgcn_s_setprio(0);
    }
    // PV chunk kc=1: key blocks 2,3
    {
        int cv = (1*4 + g);
        int b1o = ((cv ^ sw) << 4);
        f16x8 v0 = *(const f16x8*)(vB + lrow*128      + b1o);
        f16x8 v1 = *(const f16x8*)(vB + (16+lrow)*128 + b1o);
        f16x8 v2 = *(const f16x8*)(vB + (32+lrow)*128 + b1o);
        u32 a0  = __shfl(p20, la), a0h = __shfl(p30, la);
        u32 a1  = __shfl(p21, la), a1h = __shfl(p31, la);
        u32 b0  = __shfl(p20, lb), b0h = __shfl(p30, lb);
        u32 b1  = __shfl(p21, lb), b1h = __shfl(p31, lb);
        u32x4 uw = { hi ? a0h : a0, hi ? a1h : a1, hi ? b0h : b0, hi ? b1h : b1 };
        f16x8 pb = __builtin_bit_cast(f16x8, uw);
        __builtin_amdgcn_s_setprio(1);
        o0 = MFMA16(v0, pb, o0);
        o1 = MFMA16(v1, pb, o1);
        o2 = MFMA16(v2, pb, o2);
        __builtin_amdgcn_s_setprio(0);
    }
}

__global__ __launch_bounds__(256, 2) void attn_mfma(
    const f16* __restrict__ qb, const f16* __restrict__ kb,
    const f16* __restrict__ vt, float* __restrict__ out)
{
    __shared__ __align__(16) f16 ldsK[2][64*64];   // 16 KB
    __shared__ __align__(16) f16 ldsV[2][48*64];   // 12 KB

    int tid  = threadIdx.x;
    int w    = tid >> 6, l = tid & 63;
    int lrow = l & 15,  g = l >> 4;
    // XCD swizzle: 1568 = 8*196; 4 (b,h) groups per XCD -> KV L2-resident.
    int swz  = (blockIdx.x & 7)*196 + (blockIdx.x >> 3);
    int bh   = swz / 49, qblk = swz % 49;
    int h    = bh & 3, b = bh >> 2;
    int n0   = qblk*64 + w*16;

    const f16* kbb = kb + (size_t)b*MM*C_ + h*HD;
    const f16* vbb = vt + ((size_t)b*C_ + h*HD)*VT_LD;

    const f16* qrow = qb + ((size_t)b*NN + n0 + lrow)*C_ + h*HD;
    f16x8 qf0 = *(const f16x8*)(qrow + g*8);
    f16x8 qf1 = (f16x8){0,0,0,0,0,0,0,0};
    if (g < 2) qf1 = *(const f16x8*)(qrow + 32 + g*8);
    asm volatile("" :: "v"(qf0), "v"(qf1));

    float mrun = -1e30f, lrun = 0.f;
    f32x4 o0 = {0.f,0.f,0.f,0.f}, o1 = o0, o2 = o0;

    int  la = lrow + ((g & 1) << 5);
    int  lb = la + 16;
    bool hi = g >= 2;

    // prologue: stage tile 0 into buffer 0
    stage_tile(w, l, &ldsK[0][0], &ldsV[0][0], kbb, vbb, 0);

    for (int t = 0; t < 13; ++t) {
        int nb = t & 1;
        if (t < 12)
            stage_tile(w, l, &ldsK[nb^1][0], &ldsV[nb^1][0], kbb, vbb, (t+1)*64);
        __builtin_amdgcn_sched_barrier(0);
        if (t < 12) {
            if (w < 2) asm volatile("s_waitcnt vmcnt(4)" ::: "memory");
            else       asm volatile("s_waitcnt vmcnt(3)" ::: "memory");
        } else {
            asm volatile("s_waitcnt vmcnt(0)" ::: "memory");
        }
        __builtin_amdgcn_s_barrier();
        __builtin_amdgcn_sched_barrier(0);
        compute_tile64(&ldsK[nb][0], &ldsV[nb][0], qf0, qf1,
                       mrun, lrun, o0, o1, o2, lrow, g, la, lb, hi, t == 12);
        __builtin_amdgcn_sched_barrier(0);
        __builtin_amdgcn_s_barrier();
    }

    float inv = 1.f / lrun;
    f32x4 r0, r1, r2;
    #pragma unroll
    for (int r = 0; r < 4; ++r) {
        r0[r] = o0[r]*inv; r1[r] = o1[r]*inv; r2[r] = o2[r]*inv;
    }
    float* obase = out + ((size_t)b*NN + n0 + lrow)*C_ + h*HD + g*4;
    *(f32x4*)(obase)      = r0;
    *(f32x4*)(obase + 16) = r1;
    *(f32x4*)(obase + 32) = r2;
}

// ---------------------------------------------------------------------------
extern "C" void kernel_launch(void* const* d_in, const int* in_sizes, int n_in,
                              void* d_out, int out_size, void* d_ws, size_t ws_size,
                              hipStream_t stream)
{
    const float* x     = (const float*)d_in[0];
    const float* dw_q  = (const float*)d_in[3];
    const float* bnqg  = (const float*)d_in[4];
    const float* bnqb  = (const float*)d_in[5];
    const float* bnqm  = (const float*)d_in[6];
    const float* bnqv  = (const float*)d_in[7];
    const float* pw_q  = (const float*)d_in[8];
    const float* dw_kv = (const float*)d_in[9];
    const float* bnkg  = (const float*)d_in[10];
    const float* bnkb  = (const float*)d_in[11];
    const float* bnkm  = (const float*)d_in[12];
    const float* bnkvv = (const float*)d_in[13];
    const float* pw_kv = (const float*)d_in[14];
    const float* Wq    = (const float*)d_in[15];
    const float* bq    = (const float*)d_in[16];
    const float* Wk    = (const float*)d_in[17];
    const float* bk    = (const float*)d_in[18];
    const float* Wv    = (const float*)d_in[19];
    const float* bv    = (const float*)d_in[20];
    float* out = (float*)d_out;

    f16* p   = (f16*)d_ws;
    f16* Mq16  = p;  p += C_*C_;
    f16* Mk16  = p;  p += C_*C_;
    f16* Mv16  = p;  p += C_*C_;
    f16* uq16  = p;  p += (size_t)BB*NN*C_;
    f16* ukv16 = p;  p += (size_t)BB*MM*C_;
    f16* qb16  = p;  p += (size_t)BB*NN*C_ + 256;    // pad: frag tail reads
    f16* kb16  = p;  p += (size_t)BB*MM*C_ + 16384;  // pad: tail-tile staging overread
    f16* vt16  = p;  p += (size_t)BB*C_*VT_LD;

    prep_all<<<6744, 256, 0, stream>>>(
        x, dw_q, bnqg, bnqb, bnqm, bnqv,
        dw_kv, bnkg, bnkb, bnkm, bnkvv,
        Wq, Wk, Wv, pw_q, pw_kv,
        uq16, ukv16, Mq16, Mk16, Mv16, vt16);

    proj_all<<<QPB + KVPB, 256, 0, stream>>>(
        uq16, ukv16, Mq16, Mk16, Mv16, bq, bk, bv, qb16, kb16, vt16);

    attn_mfma<<<1568, 256, 0, stream>>>(qb16, kb16, vt16, out);
}